// Round 1
// baseline (880.091 us; speedup 1.0000x reference)
//
#include <hip/hip_runtime.h>
#include <hip/hip_bf16.h>
#include <math.h>

#define B_ 64
#define S_ 512
#define D_ 1024
#define H_ 512
#define WSEG 96
#define TSEG 24
#define CSEG 128
#define ESEG (TSEG + CSEG + 1) /* 153 */

// ---------------------------------------------------------------------------
// Stage 0: pack the three segment-id arrays into one int (w | t<<8 | c<<16)
// so the segsum kernel does ONE wave-uniform scalar load per token.
// ---------------------------------------------------------------------------
__global__ __launch_bounds__(256) void pack_ids_kernel(
    const int* __restrict__ w, const int* __restrict__ t,
    const int* __restrict__ c, int* __restrict__ p, int n) {
  int i = blockIdx.x * 256 + threadIdx.x;
  if (i < n) p[i] = w[i] | (t[i] << 8) | (c[i] << 16);
}

// ---------------------------------------------------------------------------
// Stage 1: scattered segment sums. Grid (D/64, B), 256 threads (4 waves).
// All 248 segment rows for a 64-wide D slice live in LDS (63.5 KB).
// Each wave handles tokens s = wave, wave+4, ... ; collisions between waves
// resolved with LDS float atomics (ds_add_f32). Bank aliasing is 2-way (free).
// ---------------------------------------------------------------------------
__global__ __launch_bounds__(256) void segsum_kernel(
    const float* __restrict__ q, const int* __restrict__ packed,
    float* __restrict__ wv, float* __restrict__ tv, float* __restrict__ cv) {
  __shared__ float acc[(WSEG + TSEG + CSEG) * 64];  // 248*64*4 = 63.5 KB
  const int tid = threadIdx.x;
  const int d0 = blockIdx.x * 64;
  const int b = blockIdx.y;

  for (int i = tid; i < (WSEG + TSEG + CSEG) * 64; i += 256) acc[i] = 0.f;
  __syncthreads();

  const int wvid = __builtin_amdgcn_readfirstlane(tid >> 6);
  const int lane = tid & 63;
  const float* qb = q + (size_t)b * S_ * D_ + d0 + lane;
  const int* pb = packed + b * S_;

  for (int s = wvid; s < S_; s += 4) {
    const int p = pb[s];                 // wave-uniform -> scalar load
    const float val = qb[(size_t)s * D_];
    atomicAdd(&acc[((p)&0xFF) * 64 + lane], val);
    atomicAdd(&acc[(WSEG + ((p >> 8) & 0xFF)) * 64 + lane], val);
    atomicAdd(&acc[(WSEG + TSEG + ((p >> 16) & 0xFF)) * 64 + lane], val);
  }
  __syncthreads();

  for (int i = tid; i < WSEG * 64; i += 256)
    wv[((size_t)b * WSEG + (i >> 6)) * D_ + d0 + (i & 63)] = acc[i];
  for (int i = tid; i < TSEG * 64; i += 256)
    tv[((size_t)b * TSEG + (i >> 6)) * D_ + d0 + (i & 63)] = acc[WSEG * 64 + i];
  for (int i = tid; i < CSEG * 64; i += 256)
    cv[((size_t)b * CSEG + (i >> 6)) * D_ + d0 + (i & 63)] =
        acc[(WSEG + TSEG) * 64 + i];
}

// ---------------------------------------------------------------------------
// Stage 2: C = tanh(A[M,1024] @ W[1024,512]) with entity-packing epilogue.
// 64x64 tile, BK=16, 256 threads, 4x4 micro-tile per thread, fp32 FMA.
// out_row = (row / rows_per_b) * out_rows_per_b + out_offset + row % rows_per_b
// lets tab/col land directly inside the [B,153,H] entity buffer.
// ---------------------------------------------------------------------------
__global__ __launch_bounds__(256) void gemm_tanh_kernel(
    const float* __restrict__ A, const float* __restrict__ W,
    float* __restrict__ out, int rows_per_b, int out_rows_per_b,
    int out_offset) {
  __shared__ float As[16][64];  // transposed: As[k][m]
  __shared__ float Bs[16][64];  // Bs[k][n]
  const int tid = threadIdx.x;
  const int m0 = blockIdx.y * 64, n0 = blockIdx.x * 64;
  const int tx = tid & 15, ty = tid >> 4;
  const int arow = tid >> 2, akk = (tid & 3) << 2;
  const int brow = tid >> 4, bcol = (tid & 15) << 2;

  const float* Ap = A + (size_t)(m0 + arow) * D_ + akk;
  const float* Wp = W + (size_t)brow * H_ + n0 + bcol;

  float accv[4][4];
#pragma unroll
  for (int i = 0; i < 4; ++i)
#pragma unroll
    for (int j = 0; j < 4; ++j) accv[i][j] = 0.f;

  for (int kt = 0; kt < D_ / 16; ++kt) {
    const float4 av = *(const float4*)(Ap + kt * 16);
    const float4 bv = *(const float4*)(Wp + (size_t)kt * 16 * H_);
    __syncthreads();
    As[akk + 0][arow] = av.x;
    As[akk + 1][arow] = av.y;
    As[akk + 2][arow] = av.z;
    As[akk + 3][arow] = av.w;
    *(float4*)&Bs[brow][bcol] = bv;
    __syncthreads();
#pragma unroll
    for (int k = 0; k < 16; ++k) {
      const float4 a = *(const float4*)&As[k][ty * 4];
      const float4 bq = *(const float4*)&Bs[k][tx * 4];
      const float ar[4] = {a.x, a.y, a.z, a.w};
      const float br[4] = {bq.x, bq.y, bq.z, bq.w};
#pragma unroll
      for (int i = 0; i < 4; ++i)
#pragma unroll
        for (int j = 0; j < 4; ++j)
          accv[i][j] = fmaf(ar[i], br[j], accv[i][j]);
    }
  }

#pragma unroll
  for (int i = 0; i < 4; ++i) {
    const int row = m0 + ty * 4 + i;
    const int orow =
        (row / rows_per_b) * out_rows_per_b + out_offset + (row % rows_per_b);
    float4 o;
    o.x = tanhf(accv[i][0]);
    o.y = tanhf(accv[i][1]);
    o.z = tanhf(accv[i][2]);
    o.w = tanhf(accv[i][3]);
    *(float4*)&out[(size_t)orow * H_ + n0 + tx * 4] = o;
  }
}

// Stage 2b: entity row 152 = no_entry (broadcast).
__global__ void ne_fill_kernel(const float* __restrict__ ne,
                               float* __restrict__ ent) {
  ent[((size_t)blockIdx.x * ESEG + (ESEG - 1)) * H_ + threadIdx.x] =
      ne[threadIdx.x];
}

// ---------------------------------------------------------------------------
// Stage 3: att = softmax(sub @ entity^T). Grid (96/8, B), 256 threads.
// 8 sub rows staged in LDS; each wave owns entities e = wave, wave+4, ...
// (coalesced h-strided loads), 8 dots per entity, 64-lane butterfly reduce.
// Softmax fully in-wave (153 entities -> 3 values/lane).
// ---------------------------------------------------------------------------
__global__ __launch_bounds__(256) void attn_kernel(
    const float* __restrict__ sub, const float* __restrict__ ent,
    float* __restrict__ out) {
  __shared__ float subs[8][H_];     // 16 KB
  __shared__ float logits[8][160];  // 5 KB
  const int tid = threadIdx.x;
  const int b = blockIdx.y;
  const int w0 = blockIdx.x * 8;

  const float* sb = sub + ((size_t)b * WSEG + w0) * H_;
  for (int i = tid; i < 8 * H_ / 4; i += 256) {
    const int r = i >> 7;
    const int h4 = (i & 127) << 2;
    *(float4*)&subs[r][h4] = *(const float4*)&sb[(size_t)r * H_ + h4];
  }
  __syncthreads();

  const int wv = __builtin_amdgcn_readfirstlane(tid >> 6);
  const int lane = tid & 63;
  const float* eb = ent + (size_t)b * ESEG * H_;

  for (int e = wv; e < ESEG; e += 4) {
    const float* ep = eb + (size_t)e * H_;
    float acc[8];
#pragma unroll
    for (int r = 0; r < 8; ++r) acc[r] = 0.f;
#pragma unroll
    for (int hh = 0; hh < H_ / 64; ++hh) {
      const int h = lane + hh * 64;
      const float evv = ep[h];
#pragma unroll
      for (int r = 0; r < 8; ++r) acc[r] = fmaf(evv, subs[r][h], acc[r]);
    }
#pragma unroll
    for (int r = 0; r < 8; ++r) {
      float v = acc[r];
#pragma unroll
      for (int off = 32; off >= 1; off >>= 1) v += __shfl_xor(v, off, 64);
      if (lane == 0) logits[r][e] = v;
    }
  }
  __syncthreads();

  for (int r = wv; r < 8; r += 4) {
    const float x0 = logits[r][lane];
    const float x1 = logits[r][lane + 64];  // lane+64 <= 127 < 153 always
    const bool has2 = (lane + 128) < ESEG;
    const float x2 = has2 ? logits[r][lane + 128] : -INFINITY;
    float m = fmaxf(fmaxf(x0, x1), x2);
#pragma unroll
    for (int off = 32; off >= 1; off >>= 1) m = fmaxf(m, __shfl_xor(m, off, 64));
    const float p0 = expf(x0 - m);
    const float p1 = expf(x1 - m);
    const float p2 = has2 ? expf(x2 - m) : 0.f;
    float ssum = p0 + p1 + p2;
#pragma unroll
    for (int off = 32; off >= 1; off >>= 1) ssum += __shfl_xor(ssum, off, 64);
    const float inv = 1.f / ssum;
    float* ob = out + ((size_t)(b * WSEG + w0 + r)) * ESEG;
    ob[lane] = p0 * inv;
    ob[lane + 64] = p1 * inv;
    if (has2) ob[lane + 128] = p2 * inv;
  }
}

// ---------------------------------------------------------------------------
extern "C" void kernel_launch(void* const* d_in, const int* in_sizes, int n_in,
                              void* d_out, int out_size, void* d_ws,
                              size_t ws_size, hipStream_t stream) {
  const float* q = (const float*)d_in[0];
  const float* Wsub = (const float*)d_in[1];
  const float* Wtab = (const float*)d_in[2];
  const float* Wcol = (const float*)d_in[3];
  const float* ne = (const float*)d_in[4];
  const int* wseg = (const int*)d_in[5];
  const int* tseg = (const int*)d_in[6];
  const int* cseg = (const int*)d_in[7];
  float* out = (float*)d_out;

  float* ws = (float*)d_ws;
  size_t off = 0;
  float* word_vecs = ws + off; off += (size_t)B_ * WSEG * D_;  // 25.2 MB
  float* tab_vecs  = ws + off; off += (size_t)B_ * TSEG * D_;  //  6.3 MB
  float* col_vecs  = ws + off; off += (size_t)B_ * CSEG * D_;  // 33.6 MB
  float* subbuf    = ws + off; off += (size_t)B_ * WSEG * H_;  // 12.6 MB
  float* ent       = ws + off; off += (size_t)B_ * ESEG * H_;  // 20.1 MB
  int* packed = (int*)(ws + off);                              // 128 KB

  pack_ids_kernel<<<(B_ * S_ + 255) / 256, 256, 0, stream>>>(wseg, tseg, cseg,
                                                             packed, B_ * S_);
  segsum_kernel<<<dim3(D_ / 64, B_), 256, 0, stream>>>(q, packed, word_vecs,
                                                       tab_vecs, col_vecs);
  gemm_tanh_kernel<<<dim3(H_ / 64, B_ * WSEG / 64), 256, 0, stream>>>(
      word_vecs, Wsub, subbuf, WSEG, WSEG, 0);
  gemm_tanh_kernel<<<dim3(H_ / 64, B_ * TSEG / 64), 256, 0, stream>>>(
      tab_vecs, Wtab, ent, TSEG, ESEG, 0);
  gemm_tanh_kernel<<<dim3(H_ / 64, B_ * CSEG / 64), 256, 0, stream>>>(
      col_vecs, Wcol, ent, CSEG, ESEG, TSEG);
  ne_fill_kernel<<<B_, H_, 0, stream>>>(ne, ent);
  attn_kernel<<<dim3(WSEG / 8, B_), 256, 0, stream>>>(subbuf, ent, out);
}

// Round 2
// 877.903 us; speedup vs baseline: 1.0025x; 1.0025x over previous
//
#include <hip/hip_runtime.h>
#include <hip/hip_bf16.h>
#include <math.h>

#define B_ 64
#define S_ 512
#define D_ 1024
#define H_ 512
#define WSEG 96
#define TSEG 24
#define CSEG 128
#define ESEG (TSEG + CSEG + 1) /* 153 */

// ---------------------------------------------------------------------------
// Stage 0: pack the three segment-id arrays into one int (w | t<<8 | c<<16).
// ---------------------------------------------------------------------------
__global__ __launch_bounds__(256) void pack_ids_kernel(
    const int* __restrict__ w, const int* __restrict__ t,
    const int* __restrict__ c, int* __restrict__ p, int n) {
  int i = blockIdx.x * 256 + threadIdx.x;
  if (i < n) p[i] = w[i] | (t[i] << 8) | (c[i] << 16);
}

// ---------------------------------------------------------------------------
// Stage 1: scattered segment sums. Grid (D/64, B), 512 threads (8 waves).
// R1 rewrite vs R0 (which was latency-bound: 260 GB/s, 24% occ):
//  - ids staged in LDS once (removes global id load from the critical path)
//  - 8 waves/block, LDS 65.5KB -> 2 blocks/CU -> 16 waves/CU (50% occ)
//  - manual 4x unroll: 4 independent 256B q loads in flight per wave
// ---------------------------------------------------------------------------
__global__ __launch_bounds__(512) void segsum_kernel(
    const float* __restrict__ q, const int* __restrict__ packed,
    float* __restrict__ wv, float* __restrict__ tv, float* __restrict__ cv) {
  __shared__ float acc[(WSEG + TSEG + CSEG) * 64];  // 248*64*4 = 63.5 KB
  __shared__ int sid[S_];                           // 2 KB
  const int tid = threadIdx.x;
  const int d0 = blockIdx.x * 64;
  const int b = blockIdx.y;

  sid[tid] = packed[b * S_ + tid];
  for (int i = tid; i < (WSEG + TSEG + CSEG) * 64; i += 512) acc[i] = 0.f;
  __syncthreads();

  const int wvid = __builtin_amdgcn_readfirstlane(tid >> 6);
  const int lane = tid & 63;
  const float* qb = q + (size_t)b * S_ * D_ + d0 + lane;

  // wave w handles token groups {4w..4w+3}, step 32 => 16 iterations
  for (int s = wvid * 4; s < S_; s += 32) {
    const int p0 = sid[s + 0];
    const int p1 = sid[s + 1];
    const int p2 = sid[s + 2];
    const int p3 = sid[s + 3];
    const float v0 = qb[(size_t)(s + 0) * D_];
    const float v1 = qb[(size_t)(s + 1) * D_];
    const float v2 = qb[(size_t)(s + 2) * D_];
    const float v3 = qb[(size_t)(s + 3) * D_];

    atomicAdd(&acc[(p0 & 0xFF) * 64 + lane], v0);
    atomicAdd(&acc[(WSEG + ((p0 >> 8) & 0xFF)) * 64 + lane], v0);
    atomicAdd(&acc[(WSEG + TSEG + ((p0 >> 16) & 0xFF)) * 64 + lane], v0);
    atomicAdd(&acc[(p1 & 0xFF) * 64 + lane], v1);
    atomicAdd(&acc[(WSEG + ((p1 >> 8) & 0xFF)) * 64 + lane], v1);
    atomicAdd(&acc[(WSEG + TSEG + ((p1 >> 16) & 0xFF)) * 64 + lane], v1);
    atomicAdd(&acc[(p2 & 0xFF) * 64 + lane], v2);
    atomicAdd(&acc[(WSEG + ((p2 >> 8) & 0xFF)) * 64 + lane], v2);
    atomicAdd(&acc[(WSEG + TSEG + ((p2 >> 16) & 0xFF)) * 64 + lane], v2);
    atomicAdd(&acc[(p3 & 0xFF) * 64 + lane], v3);
    atomicAdd(&acc[(WSEG + ((p3 >> 8) & 0xFF)) * 64 + lane], v3);
    atomicAdd(&acc[(WSEG + TSEG + ((p3 >> 16) & 0xFF)) * 64 + lane], v3);
  }
  __syncthreads();

  for (int i = tid; i < WSEG * 64; i += 512)
    wv[((size_t)b * WSEG + (i >> 6)) * D_ + d0 + (i & 63)] = acc[i];
  for (int i = tid; i < TSEG * 64; i += 512)
    tv[((size_t)b * TSEG + (i >> 6)) * D_ + d0 + (i & 63)] = acc[WSEG * 64 + i];
  for (int i = tid; i < CSEG * 64; i += 512)
    cv[((size_t)b * CSEG + (i >> 6)) * D_ + d0 + (i & 63)] =
        acc[(WSEG + TSEG) * 64 + i];
}

// ---------------------------------------------------------------------------
// Stage 2: C = tanh(A[M,1024] @ W[1024,512]) with entity-packing epilogue.
// 64x64 tile, BK=16, 256 threads, 4x4 micro-tile per thread, fp32 FMA.
// (unchanged from R0; MFMA conversion planned next round)
// ---------------------------------------------------------------------------
__global__ __launch_bounds__(256) void gemm_tanh_kernel(
    const float* __restrict__ A, const float* __restrict__ W,
    float* __restrict__ out, int rows_per_b, int out_rows_per_b,
    int out_offset) {
  __shared__ float As[16][64];  // transposed: As[k][m]
  __shared__ float Bs[16][64];  // Bs[k][n]
  const int tid = threadIdx.x;
  const int m0 = blockIdx.y * 64, n0 = blockIdx.x * 64;
  const int tx = tid & 15, ty = tid >> 4;
  const int arow = tid >> 2, akk = (tid & 3) << 2;
  const int brow = tid >> 4, bcol = (tid & 15) << 2;

  const float* Ap = A + (size_t)(m0 + arow) * D_ + akk;
  const float* Wp = W + (size_t)brow * H_ + n0 + bcol;

  float accv[4][4];
#pragma unroll
  for (int i = 0; i < 4; ++i)
#pragma unroll
    for (int j = 0; j < 4; ++j) accv[i][j] = 0.f;

  for (int kt = 0; kt < D_ / 16; ++kt) {
    const float4 av = *(const float4*)(Ap + kt * 16);
    const float4 bv = *(const float4*)(Wp + (size_t)kt * 16 * H_);
    __syncthreads();
    As[akk + 0][arow] = av.x;
    As[akk + 1][arow] = av.y;
    As[akk + 2][arow] = av.z;
    As[akk + 3][arow] = av.w;
    *(float4*)&Bs[brow][bcol] = bv;
    __syncthreads();
#pragma unroll
    for (int k = 0; k < 16; ++k) {
      const float4 a = *(const float4*)&As[k][ty * 4];
      const float4 bq = *(const float4*)&Bs[k][tx * 4];
      const float ar[4] = {a.x, a.y, a.z, a.w};
      const float br[4] = {bq.x, bq.y, bq.z, bq.w};
#pragma unroll
      for (int i = 0; i < 4; ++i)
#pragma unroll
        for (int j = 0; j < 4; ++j)
          accv[i][j] = fmaf(ar[i], br[j], accv[i][j]);
    }
  }

#pragma unroll
  for (int i = 0; i < 4; ++i) {
    const int row = m0 + ty * 4 + i;
    const int orow =
        (row / rows_per_b) * out_rows_per_b + out_offset + (row % rows_per_b);
    float4 o;
    o.x = tanhf(accv[i][0]);
    o.y = tanhf(accv[i][1]);
    o.z = tanhf(accv[i][2]);
    o.w = tanhf(accv[i][3]);
    *(float4*)&out[(size_t)orow * H_ + n0 + tx * 4] = o;
  }
}

// Stage 2b: entity row 152 = no_entry (broadcast).
__global__ void ne_fill_kernel(const float* __restrict__ ne,
                               float* __restrict__ ent) {
  ent[((size_t)blockIdx.x * ESEG + (ESEG - 1)) * H_ + threadIdx.x] =
      ne[threadIdx.x];
}

// ---------------------------------------------------------------------------
// Stage 3: att = softmax(sub @ entity^T). Grid (96/8, B), 256 threads.
// ---------------------------------------------------------------------------
__global__ __launch_bounds__(256) void attn_kernel(
    const float* __restrict__ sub, const float* __restrict__ ent,
    float* __restrict__ out) {
  __shared__ float subs[8][H_];     // 16 KB
  __shared__ float logits[8][160];  // 5 KB
  const int tid = threadIdx.x;
  const int b = blockIdx.y;
  const int w0 = blockIdx.x * 8;

  const float* sb = sub + ((size_t)b * WSEG + w0) * H_;
  for (int i = tid; i < 8 * H_ / 4; i += 256) {
    const int r = i >> 7;
    const int h4 = (i & 127) << 2;
    *(float4*)&subs[r][h4] = *(const float4*)&sb[(size_t)r * H_ + h4];
  }
  __syncthreads();

  const int wv = __builtin_amdgcn_readfirstlane(tid >> 6);
  const int lane = tid & 63;
  const float* eb = ent + (size_t)b * ESEG * H_;

  for (int e = wv; e < ESEG; e += 4) {
    const float* ep = eb + (size_t)e * H_;
    float acc[8];
#pragma unroll
    for (int r = 0; r < 8; ++r) acc[r] = 0.f;
#pragma unroll
    for (int hh = 0; hh < H_ / 64; ++hh) {
      const int h = lane + hh * 64;
      const float evv = ep[h];
#pragma unroll
      for (int r = 0; r < 8; ++r) acc[r] = fmaf(evv, subs[r][h], acc[r]);
    }
#pragma unroll
    for (int r = 0; r < 8; ++r) {
      float v = acc[r];
#pragma unroll
      for (int off = 32; off >= 1; off >>= 1) v += __shfl_xor(v, off, 64);
      if (lane == 0) logits[r][e] = v;
    }
  }
  __syncthreads();

  for (int r = wv; r < 8; r += 4) {
    const float x0 = logits[r][lane];
    const float x1 = logits[r][lane + 64];
    const bool has2 = (lane + 128) < ESEG;
    const float x2 = has2 ? logits[r][lane + 128] : -INFINITY;
    float m = fmaxf(fmaxf(x0, x1), x2);
#pragma unroll
    for (int off = 32; off >= 1; off >>= 1) m = fmaxf(m, __shfl_xor(m, off, 64));
    const float p0 = expf(x0 - m);
    const float p1 = expf(x1 - m);
    const float p2 = has2 ? expf(x2 - m) : 0.f;
    float ssum = p0 + p1 + p2;
#pragma unroll
    for (int off = 32; off >= 1; off >>= 1) ssum += __shfl_xor(ssum, off, 64);
    const float inv = 1.f / ssum;
    float* ob = out + ((size_t)(b * WSEG + w0 + r)) * ESEG;
    ob[lane] = p0 * inv;
    ob[lane + 64] = p1 * inv;
    if (has2) ob[lane + 128] = p2 * inv;
  }
}

// ---------------------------------------------------------------------------
extern "C" void kernel_launch(void* const* d_in, const int* in_sizes, int n_in,
                              void* d_out, int out_size, void* d_ws,
                              size_t ws_size, hipStream_t stream) {
  const float* q = (const float*)d_in[0];
  const float* Wsub = (const float*)d_in[1];
  const float* Wtab = (const float*)d_in[2];
  const float* Wcol = (const float*)d_in[3];
  const float* ne = (const float*)d_in[4];
  const int* wseg = (const int*)d_in[5];
  const int* tseg = (const int*)d_in[6];
  const int* cseg = (const int*)d_in[7];
  float* out = (float*)d_out;

  float* ws = (float*)d_ws;
  size_t off = 0;
  float* word_vecs = ws + off; off += (size_t)B_ * WSEG * D_;  // 25.2 MB
  float* tab_vecs  = ws + off; off += (size_t)B_ * TSEG * D_;  //  6.3 MB
  float* col_vecs  = ws + off; off += (size_t)B_ * CSEG * D_;  // 33.6 MB
  float* subbuf    = ws + off; off += (size_t)B_ * WSEG * H_;  // 12.6 MB
  float* ent       = ws + off; off += (size_t)B_ * ESEG * H_;  // 20.1 MB
  int* packed = (int*)(ws + off);                              // 128 KB

  pack_ids_kernel<<<(B_ * S_ + 255) / 256, 256, 0, stream>>>(wseg, tseg, cseg,
                                                             packed, B_ * S_);
  segsum_kernel<<<dim3(D_ / 64, B_), 512, 0, stream>>>(q, packed, word_vecs,
                                                       tab_vecs, col_vecs);
  gemm_tanh_kernel<<<dim3(H_ / 64, B_ * WSEG / 64), 256, 0, stream>>>(
      word_vecs, Wsub, subbuf, WSEG, WSEG, 0);
  gemm_tanh_kernel<<<dim3(H_ / 64, B_ * TSEG / 64), 256, 0, stream>>>(
      tab_vecs, Wtab, ent, TSEG, ESEG, 0);
  gemm_tanh_kernel<<<dim3(H_ / 64, B_ * CSEG / 64), 256, 0, stream>>>(
      col_vecs, Wcol, ent, CSEG, ESEG, TSEG);
  ne_fill_kernel<<<B_, H_, 0, stream>>>(ne, ent);
  attn_kernel<<<dim3(WSEG / 8, B_), 256, 0, stream>>>(subbuf, ent, out);
}

// Round 3
// 463.304 us; speedup vs baseline: 1.8996x; 1.8949x over previous
//
#include <hip/hip_runtime.h>
#include <hip/hip_bf16.h>
#include <math.h>

#define B_ 64
#define S_ 512
#define D_ 1024
#define H_ 512
#define WSEG 96
#define TSEG 24
#define CSEG 128
#define NSEG (WSEG + TSEG + CSEG) /* 248 */
#define ESEG (TSEG + CSEG + 1)    /* 153 */

// ---------------------------------------------------------------------------
// Stage 1a: build CSR token lists per (b, segtype, seg). One block per b.
// Integer LDS atomics only (native ds_add, no CAS loops). Slot assignment is
// rank-based (count of earlier same-seg tokens) -> fully deterministic,
// within-segment order = ascending token index.
// meta[b*248 + seg] = start | (count<<16); word segs at 0, tab at 96, col 120.
// ---------------------------------------------------------------------------
__global__ __launch_bounds__(512) void build_csr_kernel(
    const int* __restrict__ wseg, const int* __restrict__ tseg,
    const int* __restrict__ cseg, int* __restrict__ lw, int* __restrict__ lt,
    int* __restrict__ lc, int* __restrict__ meta) {
  __shared__ int wid[S_], tid_[S_], cid[S_];
  __shared__ int cw[WSEG], ct[TSEG], cc[CSEG];
  const int t = threadIdx.x;
  const int b = blockIdx.x;

  const int myw = wseg[b * S_ + t];
  const int myt = tseg[b * S_ + t];
  const int myc = cseg[b * S_ + t];
  wid[t] = myw;
  tid_[t] = myt;
  cid[t] = myc;
  if (t < WSEG) cw[t] = 0;
  if (t < TSEG) ct[t] = 0;
  if (t < CSEG) cc[t] = 0;
  __syncthreads();

  atomicAdd(&cw[myw], 1);
  atomicAdd(&ct[myt], 1);
  atomicAdd(&cc[myc], 1);
  __syncthreads();

  // exclusive scan + meta emit (serial by thread 0; 248 bins, negligible)
  if (t == 0) {
    int r = 0;
    for (int i = 0; i < WSEG; ++i) {
      const int c = cw[i];
      meta[b * NSEG + i] = r | (c << 16);
      cw[i] = r;
      r += c;
    }
    r = 0;
    for (int i = 0; i < TSEG; ++i) {
      const int c = ct[i];
      meta[b * NSEG + WSEG + i] = r | (c << 16);
      ct[i] = r;
      r += c;
    }
    r = 0;
    for (int i = 0; i < CSEG; ++i) {
      const int c = cc[i];
      meta[b * NSEG + WSEG + TSEG + i] = r | (c << 16);
      cc[i] = r;
      r += c;
    }
  }
  __syncthreads();

  // deterministic rank: #earlier tokens with same id (broadcast LDS reads)
  int rw = 0, rt = 0, rc = 0;
  for (int s = 0; s < S_; ++s) {
    const int below = (s < t) ? 1 : 0;
    rw += below & (wid[s] == myw);
    rt += below & (tid_[s] == myt);
    rc += below & (cid[s] == myc);
  }
  lw[b * S_ + cw[myw] + rw] = t;
  lt[b * S_ + ct[myt] + rt] = t;
  lc[b * S_ + cc[myc] + rc] = t;
}

// ---------------------------------------------------------------------------
// Stage 1b: gather-sum. One block per output row (B*248 blocks, 256 threads).
// Streams float4 gathers of whole 4KB q rows; q (134MB) fits in L3 so the
// 3x logical re-read is absorbed. No atomics anywhere.
// ---------------------------------------------------------------------------
__global__ __launch_bounds__(256) void gather_rows_kernel(
    const float* __restrict__ q, const int* __restrict__ lw,
    const int* __restrict__ lt, const int* __restrict__ lc,
    const int* __restrict__ meta, float* __restrict__ wv,
    float* __restrict__ tv, float* __restrict__ cv) {
  __shared__ int slist[S_];
  const int t = threadIdx.x;
  const int r = blockIdx.x;
  const int b = r / NSEG;
  const int seg = r % NSEG;

  const int m = meta[r];
  const int start = m & 0xFFFF;
  const int count = m >> 16;

  const int* list;
  float* dst;
  if (seg < WSEG) {
    list = lw;
    dst = wv + ((size_t)b * WSEG + seg) * D_;
  } else if (seg < WSEG + TSEG) {
    list = lt;
    dst = tv + ((size_t)b * TSEG + (seg - WSEG)) * D_;
  } else {
    list = lc;
    dst = cv + ((size_t)b * CSEG + (seg - WSEG - TSEG)) * D_;
  }

  for (int i = t; i < count; i += 256) slist[i] = list[b * S_ + start + i];
  __syncthreads();

  const float* qb = q + (size_t)b * S_ * D_;
  float4 acc = make_float4(0.f, 0.f, 0.f, 0.f);
  int i = 0;
  for (; i + 2 <= count; i += 2) {
    const float4 a =
        *(const float4*)(qb + (size_t)slist[i] * D_ + (t << 2));
    const float4 c =
        *(const float4*)(qb + (size_t)slist[i + 1] * D_ + (t << 2));
    acc.x += a.x + c.x;
    acc.y += a.y + c.y;
    acc.z += a.z + c.z;
    acc.w += a.w + c.w;
  }
  if (i < count) {
    const float4 a =
        *(const float4*)(qb + (size_t)slist[i] * D_ + (t << 2));
    acc.x += a.x;
    acc.y += a.y;
    acc.z += a.z;
    acc.w += a.w;
  }
  *(float4*)(dst + (t << 2)) = acc;
}

// ---------------------------------------------------------------------------
// Stage 2: C = tanh(A[M,1024] @ W[1024,512]) with entity-packing epilogue.
// 64x64 tile, BK=16, 256 threads, 4x4 micro-tile per thread, fp32 FMA.
// (unchanged; split-bf16 MFMA conversion planned next round)
// ---------------------------------------------------------------------------
__global__ __launch_bounds__(256) void gemm_tanh_kernel(
    const float* __restrict__ A, const float* __restrict__ W,
    float* __restrict__ out, int rows_per_b, int out_rows_per_b,
    int out_offset) {
  __shared__ float As[16][64];  // transposed: As[k][m]
  __shared__ float Bs[16][64];  // Bs[k][n]
  const int tid = threadIdx.x;
  const int m0 = blockIdx.y * 64, n0 = blockIdx.x * 64;
  const int tx = tid & 15, ty = tid >> 4;
  const int arow = tid >> 2, akk = (tid & 3) << 2;
  const int brow = tid >> 4, bcol = (tid & 15) << 2;

  const float* Ap = A + (size_t)(m0 + arow) * D_ + akk;
  const float* Wp = W + (size_t)brow * H_ + n0 + bcol;

  float accv[4][4];
#pragma unroll
  for (int i = 0; i < 4; ++i)
#pragma unroll
    for (int j = 0; j < 4; ++j) accv[i][j] = 0.f;

  for (int kt = 0; kt < D_ / 16; ++kt) {
    const float4 av = *(const float4*)(Ap + kt * 16);
    const float4 bv = *(const float4*)(Wp + (size_t)kt * 16 * H_);
    __syncthreads();
    As[akk + 0][arow] = av.x;
    As[akk + 1][arow] = av.y;
    As[akk + 2][arow] = av.z;
    As[akk + 3][arow] = av.w;
    *(float4*)&Bs[brow][bcol] = bv;
    __syncthreads();
#pragma unroll
    for (int k = 0; k < 16; ++k) {
      const float4 a = *(const float4*)&As[k][ty * 4];
      const float4 bq = *(const float4*)&Bs[k][tx * 4];
      const float ar[4] = {a.x, a.y, a.z, a.w};
      const float br[4] = {bq.x, bq.y, bq.z, bq.w};
#pragma unroll
      for (int i = 0; i < 4; ++i)
#pragma unroll
        for (int j = 0; j < 4; ++j)
          accv[i][j] = fmaf(ar[i], br[j], accv[i][j]);
    }
  }

#pragma unroll
  for (int i = 0; i < 4; ++i) {
    const int row = m0 + ty * 4 + i;
    const int orow =
        (row / rows_per_b) * out_rows_per_b + out_offset + (row % rows_per_b);
    float4 o;
    o.x = tanhf(accv[i][0]);
    o.y = tanhf(accv[i][1]);
    o.z = tanhf(accv[i][2]);
    o.w = tanhf(accv[i][3]);
    *(float4*)&out[(size_t)orow * H_ + n0 + tx * 4] = o;
  }
}

// Stage 2b: entity row 152 = no_entry (broadcast).
__global__ void ne_fill_kernel(const float* __restrict__ ne,
                               float* __restrict__ ent) {
  ent[((size_t)blockIdx.x * ESEG + (ESEG - 1)) * H_ + threadIdx.x] =
      ne[threadIdx.x];
}

// ---------------------------------------------------------------------------
// Stage 3: att = softmax(sub @ entity^T). Grid (96/8, B), 256 threads.
// ---------------------------------------------------------------------------
__global__ __launch_bounds__(256) void attn_kernel(
    const float* __restrict__ sub, const float* __restrict__ ent,
    float* __restrict__ out) {
  __shared__ float subs[8][H_];     // 16 KB
  __shared__ float logits[8][160];  // 5 KB
  const int tid = threadIdx.x;
  const int b = blockIdx.y;
  const int w0 = blockIdx.x * 8;

  const float* sb = sub + ((size_t)b * WSEG + w0) * H_;
  for (int i = tid; i < 8 * H_ / 4; i += 256) {
    const int r = i >> 7;
    const int h4 = (i & 127) << 2;
    *(float4*)&subs[r][h4] = *(const float4*)&sb[(size_t)r * H_ + h4];
  }
  __syncthreads();

  const int wv = __builtin_amdgcn_readfirstlane(tid >> 6);
  const int lane = tid & 63;
  const float* eb = ent + (size_t)b * ESEG * H_;

  for (int e = wv; e < ESEG; e += 4) {
    const float* ep = eb + (size_t)e * H_;
    float acc[8];
#pragma unroll
    for (int r = 0; r < 8; ++r) acc[r] = 0.f;
#pragma unroll
    for (int hh = 0; hh < H_ / 64; ++hh) {
      const int h = lane + hh * 64;
      const float evv = ep[h];
#pragma unroll
      for (int r = 0; r < 8; ++r) acc[r] = fmaf(evv, subs[r][h], acc[r]);
    }
#pragma unroll
    for (int r = 0; r < 8; ++r) {
      float v = acc[r];
#pragma unroll
      for (int off = 32; off >= 1; off >>= 1) v += __shfl_xor(v, off, 64);
      if (lane == 0) logits[r][e] = v;
    }
  }
  __syncthreads();

  for (int r = wv; r < 8; r += 4) {
    const float x0 = logits[r][lane];
    const float x1 = logits[r][lane + 64];
    const bool has2 = (lane + 128) < ESEG;
    const float x2 = has2 ? logits[r][lane + 128] : -INFINITY;
    float m = fmaxf(fmaxf(x0, x1), x2);
#pragma unroll
    for (int off = 32; off >= 1; off >>= 1) m = fmaxf(m, __shfl_xor(m, off, 64));
    const float p0 = expf(x0 - m);
    const float p1 = expf(x1 - m);
    const float p2 = has2 ? expf(x2 - m) : 0.f;
    float ssum = p0 + p1 + p2;
#pragma unroll
    for (int off = 32; off >= 1; off >>= 1) ssum += __shfl_xor(ssum, off, 64);
    const float inv = 1.f / ssum;
    float* ob = out + ((size_t)(b * WSEG + w0 + r)) * ESEG;
    ob[lane] = p0 * inv;
    ob[lane + 64] = p1 * inv;
    if (has2) ob[lane + 128] = p2 * inv;
  }
}

// ---------------------------------------------------------------------------
extern "C" void kernel_launch(void* const* d_in, const int* in_sizes, int n_in,
                              void* d_out, int out_size, void* d_ws,
                              size_t ws_size, hipStream_t stream) {
  const float* q = (const float*)d_in[0];
  const float* Wsub = (const float*)d_in[1];
  const float* Wtab = (const float*)d_in[2];
  const float* Wcol = (const float*)d_in[3];
  const float* ne = (const float*)d_in[4];
  const int* wseg = (const int*)d_in[5];
  const int* tseg = (const int*)d_in[6];
  const int* cseg = (const int*)d_in[7];
  float* out = (float*)d_out;

  float* ws = (float*)d_ws;
  size_t off = 0;
  float* word_vecs = ws + off; off += (size_t)B_ * WSEG * D_;  // 25.2 MB
  float* tab_vecs  = ws + off; off += (size_t)B_ * TSEG * D_;  //  6.3 MB
  float* col_vecs  = ws + off; off += (size_t)B_ * CSEG * D_;  // 33.6 MB
  float* subbuf    = ws + off; off += (size_t)B_ * WSEG * H_;  // 12.6 MB
  float* ent       = ws + off; off += (size_t)B_ * ESEG * H_;  // 20.1 MB
  int* lw   = (int*)(ws + off); off += B_ * S_;                // 128 KB
  int* lt   = (int*)(ws + off); off += B_ * S_;                // 128 KB
  int* lc   = (int*)(ws + off); off += B_ * S_;                // 128 KB
  int* meta = (int*)(ws + off); off += B_ * NSEG;              //  62 KB

  build_csr_kernel<<<B_, 512, 0, stream>>>(wseg, tseg, cseg, lw, lt, lc, meta);
  gather_rows_kernel<<<B_ * NSEG, 256, 0, stream>>>(q, lw, lt, lc, meta,
                                                    word_vecs, tab_vecs,
                                                    col_vecs);
  gemm_tanh_kernel<<<dim3(H_ / 64, B_ * WSEG / 64), 256, 0, stream>>>(
      word_vecs, Wsub, subbuf, WSEG, WSEG, 0);
  gemm_tanh_kernel<<<dim3(H_ / 64, B_ * TSEG / 64), 256, 0, stream>>>(
      tab_vecs, Wtab, ent, TSEG, ESEG, 0);
  gemm_tanh_kernel<<<dim3(H_ / 64, B_ * CSEG / 64), 256, 0, stream>>>(
      col_vecs, Wcol, ent, CSEG, ESEG, TSEG);
  ne_fill_kernel<<<B_, H_, 0, stream>>>(ne, ent);
  attn_kernel<<<dim3(WSEG / 8, B_), 256, 0, stream>>>(subbuf, ent, out);
}

// Round 4
// 263.700 us; speedup vs baseline: 3.3375x; 1.7569x over previous
//
#include <hip/hip_runtime.h>
#include <hip/hip_bf16.h>
#include <math.h>

#define B_ 64
#define S_ 512
#define D_ 1024
#define H_ 512
#define WSEG 96
#define TSEG 24
#define CSEG 128
#define NSEG (WSEG + TSEG + CSEG) /* 248 */
#define ESEG (TSEG + CSEG + 1)    /* 153 */
#define MTOT (B_ * NSEG)          /* 15872 A rows: [word 6144][tab 1536][col 8192] */

typedef __bf16 bf16x8 __attribute__((ext_vector_type(8)));
typedef __bf16 bf16x4 __attribute__((ext_vector_type(4)));
typedef float f32x4 __attribute__((ext_vector_type(4)));

#define GL16(g, l)                                                      \
  __builtin_amdgcn_global_load_lds(                                     \
      (const __attribute__((address_space(1))) void*)(g),               \
      (__attribute__((address_space(3))) void*)(l), 16, 0, 0)

__device__ inline float tanh_fast(float x) {
  const float xc = fminf(12.f, fmaxf(-12.f, x));
  const float e = __expf(2.f * xc);
  return (e - 1.f) * __builtin_amdgcn_rcpf(e + 1.f);
}

// ---------------------------------------------------------------------------
// Stage 1a: build CSR token lists per (b, segtype, seg). One block per b.
// Integer LDS atomics only; deterministic rank-based slot assignment.
// ---------------------------------------------------------------------------
__global__ __launch_bounds__(512) void build_csr_kernel(
    const int* __restrict__ wseg, const int* __restrict__ tseg,
    const int* __restrict__ cseg, int* __restrict__ lw, int* __restrict__ lt,
    int* __restrict__ lc, int* __restrict__ meta) {
  __shared__ int wid[S_], tid_[S_], cid[S_];
  __shared__ int cw[WSEG], ct[TSEG], cc[CSEG];
  const int t = threadIdx.x;
  const int b = blockIdx.x;

  const int myw = wseg[b * S_ + t];
  const int myt = tseg[b * S_ + t];
  const int myc = cseg[b * S_ + t];
  wid[t] = myw;
  tid_[t] = myt;
  cid[t] = myc;
  if (t < WSEG) cw[t] = 0;
  if (t < TSEG) ct[t] = 0;
  if (t < CSEG) cc[t] = 0;
  __syncthreads();

  atomicAdd(&cw[myw], 1);
  atomicAdd(&ct[myt], 1);
  atomicAdd(&cc[myc], 1);
  __syncthreads();

  if (t == 0) {
    int r = 0;
    for (int i = 0; i < WSEG; ++i) {
      const int c = cw[i];
      meta[b * NSEG + i] = r | (c << 16);
      cw[i] = r;
      r += c;
    }
    r = 0;
    for (int i = 0; i < TSEG; ++i) {
      const int c = ct[i];
      meta[b * NSEG + WSEG + i] = r | (c << 16);
      ct[i] = r;
      r += c;
    }
    r = 0;
    for (int i = 0; i < CSEG; ++i) {
      const int c = cc[i];
      meta[b * NSEG + WSEG + TSEG + i] = r | (c << 16);
      cc[i] = r;
      r += c;
    }
  }
  __syncthreads();

  int rw = 0, rt = 0, rc = 0;
  for (int s = 0; s < S_; ++s) {
    const int below = (s < t) ? 1 : 0;
    rw += below & (wid[s] == myw);
    rt += below & (tid_[s] == myt);
    rc += below & (cid[s] == myc);
  }
  lw[b * S_ + cw[myw] + rw] = t;
  lt[b * S_ + ct[myt] + rt] = t;
  lc[b * S_ + cc[myc] + rc] = t;
}

// ---------------------------------------------------------------------------
// Stage 1b: gather-sum -> A matrix in SPLIT bf16 (hi + lo residual).
// One block per A row (B*248 blocks, 256 threads). A row ordering:
// [0..6143]=word (b*96+w), [6144..7679]=tab (b*24+t), [7680..15871]=col.
// ---------------------------------------------------------------------------
__global__ __launch_bounds__(256) void gather_rows_kernel(
    const float* __restrict__ q, const int* __restrict__ lw,
    const int* __restrict__ lt, const int* __restrict__ lc,
    const int* __restrict__ meta, __bf16* __restrict__ Ah,
    __bf16* __restrict__ Al) {
  __shared__ int slist[S_];
  const int t = threadIdx.x;
  const int r = blockIdx.x;
  const int b = r / NSEG;
  const int seg = r % NSEG;

  const int m = meta[r];
  const int start = m & 0xFFFF;
  const int count = m >> 16;

  const int* list;
  int arow;
  if (seg < WSEG) {
    list = lw;
    arow = b * WSEG + seg;
  } else if (seg < WSEG + TSEG) {
    list = lt;
    arow = B_ * WSEG + b * TSEG + (seg - WSEG);
  } else {
    list = lc;
    arow = B_ * (WSEG + TSEG) + b * CSEG + (seg - WSEG - TSEG);
  }

  for (int i = t; i < count; i += 256) slist[i] = list[b * S_ + start + i];
  __syncthreads();

  const float* qb = q + (size_t)b * S_ * D_;
  float4 acc = make_float4(0.f, 0.f, 0.f, 0.f);
  int i = 0;
  for (; i + 2 <= count; i += 2) {
    const float4 a = *(const float4*)(qb + (size_t)slist[i] * D_ + (t << 2));
    const float4 c =
        *(const float4*)(qb + (size_t)slist[i + 1] * D_ + (t << 2));
    acc.x += a.x + c.x;
    acc.y += a.y + c.y;
    acc.z += a.z + c.z;
    acc.w += a.w + c.w;
  }
  if (i < count) {
    const float4 a = *(const float4*)(qb + (size_t)slist[i] * D_ + (t << 2));
    acc.x += a.x;
    acc.y += a.y;
    acc.z += a.z;
    acc.w += a.w;
  }
  const __bf16 h0 = (__bf16)acc.x, h1 = (__bf16)acc.y, h2 = (__bf16)acc.z,
               h3 = (__bf16)acc.w;
  const bf16x4 hv = {h0, h1, h2, h3};
  const bf16x4 lv = {(__bf16)(acc.x - (float)h0), (__bf16)(acc.y - (float)h1),
                     (__bf16)(acc.z - (float)h2), (__bf16)(acc.w - (float)h3)};
  *(bf16x4*)(Ah + (size_t)arow * D_ + (t << 2)) = hv;
  *(bf16x4*)(Al + (size_t)arow * D_ + (t << 2)) = lv;
}

// ---------------------------------------------------------------------------
// Stage 1c: transpose weights fp32 [1024][512] -> Wt hi/lo bf16 [3][512][1024]
// so GEMM B-fragments stage identically to A. One-time, ~6 MB.
// ---------------------------------------------------------------------------
__global__ __launch_bounds__(256) void prep_w_kernel(
    const float* __restrict__ Ws, const float* __restrict__ Wt_,
    const float* __restrict__ Wc, __bf16* __restrict__ Wth,
    __bf16* __restrict__ Wtl) {
  __shared__ float tile[64][65];
  const int z = blockIdx.z;
  const float* W = (z == 0) ? Ws : ((z == 1) ? Wt_ : Wc);
  const int k0 = blockIdx.y * 64, n0 = blockIdx.x * 64;
  const int tx = threadIdx.x & 63, ty = threadIdx.x >> 6;

#pragma unroll
  for (int i = 0; i < 16; ++i) {
    const int kl = i * 4 + ty;
    tile[kl][tx] = W[(size_t)(k0 + kl) * H_ + n0 + tx];
  }
  __syncthreads();
  __bf16* oh = Wth + (size_t)z * H_ * D_;
  __bf16* ol = Wtl + (size_t)z * H_ * D_;
#pragma unroll
  for (int i = 0; i < 16; ++i) {
    const int nl = i * 4 + ty;
    const float v = tile[tx][nl];
    const __bf16 h = (__bf16)v;
    oh[(size_t)(n0 + nl) * D_ + k0 + tx] = h;
    ol[(size_t)(n0 + nl) * D_ + k0 + tx] = (__bf16)(v - (float)h);
  }
}

// ---------------------------------------------------------------------------
// Stage 2: split-bf16 MFMA GEMM, C = tanh(A @ W), 128x128 tile, BK=64.
// 4 waves, each 64x64 via 4x4 fragments of mfma_f32_16x16x32_bf16, 3 passes
// (hi*hi + hi*lo + lo*hi). global_load_lds staging with pre-swizzled global
// source + XOR-swizzled ds_read (rule #21); swizzle byte^=((row&7)<<4).
// Epilogue packs word->sub, tab/col->ent[B,153,H] and applies tanh.
// ---------------------------------------------------------------------------
__global__ __launch_bounds__(256) void gemm3_kernel(
    const __bf16* __restrict__ Ah, const __bf16* __restrict__ Al,
    const __bf16* __restrict__ Wth, const __bf16* __restrict__ Wtl,
    float* __restrict__ sub_out, float* __restrict__ ent_out, int m_offset) {
  __shared__ __align__(16) char smem[65536];
  char* sAh = smem;            // 16 KB: [128 rows][64 k] bf16, swizzled
  char* sAl = smem + 16384;
  char* sBh = smem + 32768;    // [128 n][64 k]
  char* sBl = smem + 49152;

  const int tid = threadIdx.x;
  const int wid = tid >> 6;
  const int lane = tid & 63;
  const int m0 = m_offset + blockIdx.y * 128;
  const int n0 = blockIdx.x * 128;
  const int id = (m0 < B_ * WSEG) ? 0 : ((m0 < B_ * (WSEG + TSEG)) ? 1 : 2);

  const __bf16* Bh_g = Wth + (size_t)id * H_ * D_ + (size_t)n0 * D_;
  const __bf16* Bl_g = Wtl + (size_t)id * H_ * D_ + (size_t)n0 * D_;
  const __bf16* Ah_g = Ah + (size_t)m0 * D_;
  const __bf16* Al_g = Al + (size_t)m0 * D_;

  const int rsub = lane >> 3;          // row within 8-row staging group
  const int csrc = (lane & 7) ^ rsub;  // pre-swizzled source chunk

  // per-lane fragment read geometry
  const int wr = wid >> 1, wc = wid & 1;
  const int arow0 = wr * 64 + (lane & 15);
  const int brow0 = wc * 64 + (lane & 15);
  const int cbase = (lane >> 4) * 16;
  const int sw = (lane & 7) << 4;

  f32x4 acc[4][4] = {};

#pragma unroll 1
  for (int kt = 0; kt < D_ / 64; ++kt) {
    __syncthreads();  // previous compute done; LDS reusable
    const size_t kofs = (size_t)kt * 64 + (size_t)csrc * 8;
#pragma unroll
    for (int j = 0; j < 4; ++j) {
      const int i = wid * 4 + j;                 // staging instr 0..15
      const size_t grow = (size_t)(i * 8 + rsub) * D_ + kofs;
      GL16(Ah_g + grow, sAh + i * 1024);
      GL16(Al_g + grow, sAl + i * 1024);
      GL16(Bh_g + grow, sBh + i * 1024);
      GL16(Bl_g + grow, sBl + i * 1024);
    }
    __syncthreads();  // implicit vmcnt(0) drain -> LDS valid

#pragma unroll
    for (int ks = 0; ks < 2; ++ks) {
      const int cc = ((cbase + ks * 64) ^ sw);
      bf16x8 ah[4], al_[4], bh[4], bl_[4];
#pragma unroll
      for (int mi = 0; mi < 4; ++mi) {
        const int off = (arow0 + mi * 16) * 128 + cc;
        ah[mi] = *(const bf16x8*)(sAh + off);
        al_[mi] = *(const bf16x8*)(sAl + off);
      }
#pragma unroll
      for (int ni = 0; ni < 4; ++ni) {
        const int off = (brow0 + ni * 16) * 128 + cc;
        bh[ni] = *(const bf16x8*)(sBh + off);
        bl_[ni] = *(const bf16x8*)(sBl + off);
      }
#pragma unroll
      for (int mi = 0; mi < 4; ++mi)
#pragma unroll
        for (int ni = 0; ni < 4; ++ni) {
          acc[mi][ni] = __builtin_amdgcn_mfma_f32_16x16x32_bf16(
              ah[mi], bh[ni], acc[mi][ni], 0, 0, 0);
          acc[mi][ni] = __builtin_amdgcn_mfma_f32_16x16x32_bf16(
              ah[mi], bl_[ni], acc[mi][ni], 0, 0, 0);
          acc[mi][ni] = __builtin_amdgcn_mfma_f32_16x16x32_bf16(
              al_[mi], bh[ni], acc[mi][ni], 0, 0, 0);
        }
    }
  }

  // epilogue: C row = (lane>>4)*4 + reg, col = lane&15 (m89-verified)
  const int rowb = m0 + wr * 64 + (lane >> 4) * 4;
  const int colb = n0 + wc * 64 + (lane & 15);
#pragma unroll
  for (int mi = 0; mi < 4; ++mi)
#pragma unroll
    for (int ni = 0; ni < 4; ++ni) {
      const f32x4 v = acc[mi][ni];
      const int col = colb + ni * 16;
#pragma unroll
      for (int r = 0; r < 4; ++r) {
        const int row = rowb + mi * 16 + r;
        const float val = tanh_fast(v[r]);
        if (id == 0) {
          sub_out[(size_t)row * H_ + col] = val;
        } else if (id == 1) {
          const int lr = row - B_ * WSEG;
          const int bb = lr / TSEG;
          const int rr = lr - bb * TSEG;
          ent_out[((size_t)bb * ESEG + rr) * H_ + col] = val;
        } else {
          const int lr = row - B_ * (WSEG + TSEG);
          const int bb = lr >> 7;
          const int rr = lr & 127;
          ent_out[((size_t)bb * ESEG + TSEG + rr) * H_ + col] = val;
        }
      }
    }
}

// Stage 2b: entity row 152 = no_entry (raw broadcast, not tanh'd).
__global__ void ne_fill_kernel(const float* __restrict__ ne,
                               float* __restrict__ ent) {
  ent[((size_t)blockIdx.x * ESEG + (ESEG - 1)) * H_ + threadIdx.x] =
      ne[threadIdx.x];
}

// ---------------------------------------------------------------------------
// Stage 3: att = softmax(sub @ entity^T). Grid (96/8, B), 256 threads.
// ---------------------------------------------------------------------------
__global__ __launch_bounds__(256) void attn_kernel(
    const float* __restrict__ sub, const float* __restrict__ ent,
    float* __restrict__ out) {
  __shared__ float subs[8][H_];
  __shared__ float logits[8][160];
  const int tid = threadIdx.x;
  const int b = blockIdx.y;
  const int w0 = blockIdx.x * 8;

  const float* sb = sub + ((size_t)b * WSEG + w0) * H_;
  for (int i = tid; i < 8 * H_ / 4; i += 256) {
    const int r = i >> 7;
    const int h4 = (i & 127) << 2;
    *(float4*)&subs[r][h4] = *(const float4*)&sb[(size_t)r * H_ + h4];
  }
  __syncthreads();

  const int wv = __builtin_amdgcn_readfirstlane(tid >> 6);
  const int lane = tid & 63;
  const float* eb = ent + (size_t)b * ESEG * H_;

  for (int e = wv; e < ESEG; e += 4) {
    const float* ep = eb + (size_t)e * H_;
    float acc[8];
#pragma unroll
    for (int r = 0; r < 8; ++r) acc[r] = 0.f;
#pragma unroll
    for (int hh = 0; hh < H_ / 64; ++hh) {
      const int h = lane + hh * 64;
      const float evv = ep[h];
#pragma unroll
      for (int r = 0; r < 8; ++r) acc[r] = fmaf(evv, subs[r][h], acc[r]);
    }
#pragma unroll
    for (int r = 0; r < 8; ++r) {
      float v = acc[r];
#pragma unroll
      for (int off = 32; off >= 1; off >>= 1) v += __shfl_xor(v, off, 64);
      if (lane == 0) logits[r][e] = v;
    }
  }
  __syncthreads();

  for (int r = wv; r < 8; r += 4) {
    const float x0 = logits[r][lane];
    const float x1 = logits[r][lane + 64];
    const bool has2 = (lane + 128) < ESEG;
    const float x2 = has2 ? logits[r][lane + 128] : -INFINITY;
    float m = fmaxf(fmaxf(x0, x1), x2);
#pragma unroll
    for (int off = 32; off >= 1; off >>= 1) m = fmaxf(m, __shfl_xor(m, off, 64));
    const float p0 = expf(x0 - m);
    const float p1 = expf(x1 - m);
    const float p2 = has2 ? expf(x2 - m) : 0.f;
    float ssum = p0 + p1 + p2;
#pragma unroll
    for (int off = 32; off >= 1; off >>= 1) ssum += __shfl_xor(ssum, off, 64);
    const float inv = 1.f / ssum;
    float* ob = out + ((size_t)(b * WSEG + w0 + r)) * ESEG;
    ob[lane] = p0 * inv;
    ob[lane + 64] = p1 * inv;
    if (has2) ob[lane + 128] = p2 * inv;
  }
}

// ---------------------------------------------------------------------------
extern "C" void kernel_launch(void* const* d_in, const int* in_sizes, int n_in,
                              void* d_out, int out_size, void* d_ws,
                              size_t ws_size, hipStream_t stream) {
  const float* q = (const float*)d_in[0];
  const float* Wsub = (const float*)d_in[1];
  const float* Wtab = (const float*)d_in[2];
  const float* Wcol = (const float*)d_in[3];
  const float* ne = (const float*)d_in[4];
  const int* wseg = (const int*)d_in[5];
  const int* tseg = (const int*)d_in[6];
  const int* cseg = (const int*)d_in[7];
  float* out = (float*)d_out;

  // workspace layout (bytes), peak 91.8 MB:
  char* w = (char*)d_ws;
  __bf16* Ah = (__bf16*)(w);                       // 32,505,856 B
  __bf16* Al = (__bf16*)(w + 32505856);            // 32,505,856 B
  float* ent = (float*)(w + 65011712);             // 20,054,016 B
  __bf16* Wth = (__bf16*)(w + 85065728);           //  3,145,728 B
  __bf16* Wtl = (__bf16*)(w + 88211456);           //  3,145,728 B
  int* lw = (int*)(w + 91357184);
  int* lt = (int*)(w + 91488256);
  int* lc = (int*)(w + 91619328);
  int* meta = (int*)(w + 91750400);                // ends 91,813,888
  // subbuf overlays dead tab/col A_hi rows (word GEMM runs last, reads only
  // A rows 0..6143 = bytes 0..12.58MB; overlay starts at 12.58MB).
  float* subbuf = (float*)(w + 12582912);          // 12,582,912 B

  build_csr_kernel<<<B_, 512, 0, stream>>>(wseg, tseg, cseg, lw, lt, lc, meta);
  gather_rows_kernel<<<B_ * NSEG, 256, 0, stream>>>(q, lw, lt, lc, meta, Ah,
                                                    Al);
  prep_w_kernel<<<dim3(8, 16, 3), 256, 0, stream>>>(Wsub, Wtab, Wcol, Wth,
                                                    Wtl);
  // tab+col GEMM first (reads A rows 6144.., writes ent)
  gemm3_kernel<<<dim3(4, 76), 256, 0, stream>>>(Ah, Al, Wth, Wtl, subbuf, ent,
                                                B_ * WSEG);
  ne_fill_kernel<<<B_, H_, 0, stream>>>(ne, ent);
  // word GEMM (reads A rows 0..6143, writes subbuf overlay)
  gemm3_kernel<<<dim3(4, 48), 256, 0, stream>>>(Ah, Al, Wth, Wtl, subbuf, ent,
                                                0);
  attn_kernel<<<dim3(WSEG / 8, B_), 256, 0, stream>>>(subbuf, ent, out);
}

// Round 5
// 217.935 us; speedup vs baseline: 4.0383x; 1.2100x over previous
//
#include <hip/hip_runtime.h>
#include <hip/hip_bf16.h>
#include <math.h>

#define B_ 64
#define S_ 512
#define D_ 1024
#define H_ 512
#define WSEG 96
#define TSEG 24
#define CSEG 128
#define NSEG (WSEG + TSEG + CSEG) /* 248 */
#define ESEG (TSEG + CSEG + 1)    /* 153 */
#define EPAD 160                  /* ent rows padded per batch */

typedef __bf16 bf16x8 __attribute__((ext_vector_type(8)));
typedef __bf16 bf16x4 __attribute__((ext_vector_type(4)));
typedef float f32x4 __attribute__((ext_vector_type(4)));

#define GL16(g, l)                                                      \
  __builtin_amdgcn_global_load_lds(                                     \
      (const __attribute__((address_space(1))) void*)(g),               \
      (__attribute__((address_space(3))) void*)(l), 16, 0, 0)

__device__ inline float tanh_fast(float x) {
  const float xc = fminf(12.f, fmaxf(-12.f, x));
  const float e = __expf(2.f * xc);
  return (e - 1.f) * __builtin_amdgcn_rcpf(e + 1.f);
}

// ---------------------------------------------------------------------------
// Stage 1a: build CSR token lists per (b, segtype, seg). One block per b.
// ---------------------------------------------------------------------------
__global__ __launch_bounds__(512) void build_csr_kernel(
    const int* __restrict__ wseg, const int* __restrict__ tseg,
    const int* __restrict__ cseg, int* __restrict__ lw, int* __restrict__ lt,
    int* __restrict__ lc, int* __restrict__ meta) {
  __shared__ int wid[S_], tid_[S_], cid[S_];
  __shared__ int cw[WSEG], ct[TSEG], cc[CSEG];
  const int t = threadIdx.x;
  const int b = blockIdx.x;

  const int myw = wseg[b * S_ + t];
  const int myt = tseg[b * S_ + t];
  const int myc = cseg[b * S_ + t];
  wid[t] = myw;
  tid_[t] = myt;
  cid[t] = myc;
  if (t < WSEG) cw[t] = 0;
  if (t < TSEG) ct[t] = 0;
  if (t < CSEG) cc[t] = 0;
  __syncthreads();

  atomicAdd(&cw[myw], 1);
  atomicAdd(&ct[myt], 1);
  atomicAdd(&cc[myc], 1);
  __syncthreads();

  if (t == 0) {
    int r = 0;
    for (int i = 0; i < WSEG; ++i) {
      const int c = cw[i];
      meta[b * NSEG + i] = r | (c << 16);
      cw[i] = r;
      r += c;
    }
    r = 0;
    for (int i = 0; i < TSEG; ++i) {
      const int c = ct[i];
      meta[b * NSEG + WSEG + i] = r | (c << 16);
      ct[i] = r;
      r += c;
    }
    r = 0;
    for (int i = 0; i < CSEG; ++i) {
      const int c = cc[i];
      meta[b * NSEG + WSEG + TSEG + i] = r | (c << 16);
      cc[i] = r;
      r += c;
    }
  }
  __syncthreads();

  int rw = 0, rt = 0, rc = 0;
  for (int s = 0; s < S_; ++s) {
    const int below = (s < t) ? 1 : 0;
    rw += below & (wid[s] == myw);
    rt += below & (tid_[s] == myt);
    rc += below & (cid[s] == myc);
  }
  lw[b * S_ + cw[myw] + rw] = t;
  lt[b * S_ + ct[myt] + rt] = t;
  lc[b * S_ + cc[myc] + rc] = t;
}

// ---------------------------------------------------------------------------
// Stage 1b: gather-sum -> A matrix in SPLIT bf16 (hi + lo residual).
// ---------------------------------------------------------------------------
__global__ __launch_bounds__(256) void gather_rows_kernel(
    const float* __restrict__ q, const int* __restrict__ lw,
    const int* __restrict__ lt, const int* __restrict__ lc,
    const int* __restrict__ meta, __bf16* __restrict__ Ah,
    __bf16* __restrict__ Al) {
  __shared__ int slist[S_];
  const int t = threadIdx.x;
  const int r = blockIdx.x;
  const int b = r / NSEG;
  const int seg = r % NSEG;

  const int m = meta[r];
  const int start = m & 0xFFFF;
  const int count = m >> 16;

  const int* list;
  int arow;
  if (seg < WSEG) {
    list = lw;
    arow = b * WSEG + seg;
  } else if (seg < WSEG + TSEG) {
    list = lt;
    arow = B_ * WSEG + b * TSEG + (seg - WSEG);
  } else {
    list = lc;
    arow = B_ * (WSEG + TSEG) + b * CSEG + (seg - WSEG - TSEG);
  }

  for (int i = t; i < count; i += 256) slist[i] = list[b * S_ + start + i];
  __syncthreads();

  const float* qb = q + (size_t)b * S_ * D_;
  float4 acc = make_float4(0.f, 0.f, 0.f, 0.f);
  int i = 0;
  for (; i + 2 <= count; i += 2) {
    const float4 a = *(const float4*)(qb + (size_t)slist[i] * D_ + (t << 2));
    const float4 c =
        *(const float4*)(qb + (size_t)slist[i + 1] * D_ + (t << 2));
    acc.x += a.x + c.x;
    acc.y += a.y + c.y;
    acc.z += a.z + c.z;
    acc.w += a.w + c.w;
  }
  if (i < count) {
    const float4 a = *(const float4*)(qb + (size_t)slist[i] * D_ + (t << 2));
    acc.x += a.x;
    acc.y += a.y;
    acc.z += a.z;
    acc.w += a.w;
  }
  const __bf16 h0 = (__bf16)acc.x, h1 = (__bf16)acc.y, h2 = (__bf16)acc.z,
               h3 = (__bf16)acc.w;
  const bf16x4 hv = {h0, h1, h2, h3};
  const bf16x4 lv = {(__bf16)(acc.x - (float)h0), (__bf16)(acc.y - (float)h1),
                     (__bf16)(acc.z - (float)h2), (__bf16)(acc.w - (float)h3)};
  *(bf16x4*)(Ah + (size_t)arow * D_ + (t << 2)) = hv;
  *(bf16x4*)(Al + (size_t)arow * D_ + (t << 2)) = lv;
}

// ---------------------------------------------------------------------------
// Stage 1c: transpose weights -> Wt hi/lo bf16 [3][512][1024].
// ---------------------------------------------------------------------------
__global__ __launch_bounds__(256) void prep_w_kernel(
    const float* __restrict__ Ws, const float* __restrict__ Wt_,
    const float* __restrict__ Wc, __bf16* __restrict__ Wth,
    __bf16* __restrict__ Wtl) {
  __shared__ float tile[64][65];
  const int z = blockIdx.z;
  const float* W = (z == 0) ? Ws : ((z == 1) ? Wt_ : Wc);
  const int k0 = blockIdx.y * 64, n0 = blockIdx.x * 64;
  const int tx = threadIdx.x & 63, ty = threadIdx.x >> 6;

#pragma unroll
  for (int i = 0; i < 16; ++i) {
    const int kl = i * 4 + ty;
    tile[kl][tx] = W[(size_t)(k0 + kl) * H_ + n0 + tx];
  }
  __syncthreads();
  __bf16* oh = Wth + (size_t)z * H_ * D_;
  __bf16* ol = Wtl + (size_t)z * H_ * D_;
#pragma unroll
  for (int i = 0; i < 16; ++i) {
    const int nl = i * 4 + ty;
    const float v = tile[tx][nl];
    const __bf16 h = (__bf16)v;
    oh[(size_t)(n0 + nl) * D_ + k0 + tx] = h;
    ol[(size_t)(n0 + nl) * D_ + k0 + tx] = (__bf16)(v - (float)h);
  }
}

// ---------------------------------------------------------------------------
// Stage 2: split-bf16 MFMA GEMM, 128x128 tile, BK=64, tanh epilogue.
// Outputs hi/lo bf16: word rows -> sub_h/sub_l [B*96][512];
// tab/col rows -> ent_h/ent_l [B][160][512] (tab at 0..23, col at 24..151).
// ---------------------------------------------------------------------------
__global__ __launch_bounds__(256) void gemm3_kernel(
    const __bf16* __restrict__ Ah, const __bf16* __restrict__ Al,
    const __bf16* __restrict__ Wth, const __bf16* __restrict__ Wtl,
    __bf16* __restrict__ sub_h, __bf16* __restrict__ sub_l,
    __bf16* __restrict__ ent_h, __bf16* __restrict__ ent_l, int m_offset) {
  __shared__ __align__(16) char smem[65536];
  char* sAh = smem;
  char* sAl = smem + 16384;
  char* sBh = smem + 32768;
  char* sBl = smem + 49152;

  const int tid = threadIdx.x;
  const int wid = tid >> 6;
  const int lane = tid & 63;
  const int m0 = m_offset + blockIdx.y * 128;
  const int n0 = blockIdx.x * 128;
  const int id = (m0 < B_ * WSEG) ? 0 : ((m0 < B_ * (WSEG + TSEG)) ? 1 : 2);

  const __bf16* Bh_g = Wth + (size_t)id * H_ * D_ + (size_t)n0 * D_;
  const __bf16* Bl_g = Wtl + (size_t)id * H_ * D_ + (size_t)n0 * D_;
  const __bf16* Ah_g = Ah + (size_t)m0 * D_;
  const __bf16* Al_g = Al + (size_t)m0 * D_;

  const int rsub = lane >> 3;
  const int csrc = (lane & 7) ^ rsub;

  const int wr = wid >> 1, wc = wid & 1;
  const int arow0 = wr * 64 + (lane & 15);
  const int brow0 = wc * 64 + (lane & 15);
  const int cbase = (lane >> 4) * 16;
  const int sw = (lane & 7) << 4;

  f32x4 acc[4][4] = {};

#pragma unroll 1
  for (int kt = 0; kt < D_ / 64; ++kt) {
    __syncthreads();
    const size_t kofs = (size_t)kt * 64 + (size_t)csrc * 8;
#pragma unroll
    for (int j = 0; j < 4; ++j) {
      const int i = wid * 4 + j;
      const size_t grow = (size_t)(i * 8 + rsub) * D_ + kofs;
      GL16(Ah_g + grow, sAh + i * 1024);
      GL16(Al_g + grow, sAl + i * 1024);
      GL16(Bh_g + grow, sBh + i * 1024);
      GL16(Bl_g + grow, sBl + i * 1024);
    }
    __syncthreads();

#pragma unroll
    for (int ks = 0; ks < 2; ++ks) {
      const int cc = ((cbase + ks * 64) ^ sw);
      bf16x8 ah[4], al_[4], bh[4], bl_[4];
#pragma unroll
      for (int mi = 0; mi < 4; ++mi) {
        const int off = (arow0 + mi * 16) * 128 + cc;
        ah[mi] = *(const bf16x8*)(sAh + off);
        al_[mi] = *(const bf16x8*)(sAl + off);
      }
#pragma unroll
      for (int ni = 0; ni < 4; ++ni) {
        const int off = (brow0 + ni * 16) * 128 + cc;
        bh[ni] = *(const bf16x8*)(sBh + off);
        bl_[ni] = *(const bf16x8*)(sBl + off);
      }
#pragma unroll
      for (int mi = 0; mi < 4; ++mi)
#pragma unroll
        for (int ni = 0; ni < 4; ++ni) {
          acc[mi][ni] = __builtin_amdgcn_mfma_f32_16x16x32_bf16(
              ah[mi], bh[ni], acc[mi][ni], 0, 0, 0);
          acc[mi][ni] = __builtin_amdgcn_mfma_f32_16x16x32_bf16(
              ah[mi], bl_[ni], acc[mi][ni], 0, 0, 0);
          acc[mi][ni] = __builtin_amdgcn_mfma_f32_16x16x32_bf16(
              al_[mi], bh[ni], acc[mi][ni], 0, 0, 0);
        }
    }
  }

  const int rowb = m0 + wr * 64 + (lane >> 4) * 4;
  const int colb = n0 + wc * 64 + (lane & 15);
#pragma unroll
  for (int mi = 0; mi < 4; ++mi)
#pragma unroll
    for (int ni = 0; ni < 4; ++ni) {
      const f32x4 v = acc[mi][ni];
      const int col = colb + ni * 16;
#pragma unroll
      for (int r = 0; r < 4; ++r) {
        const int row = rowb + mi * 16 + r;
        const float val = tanh_fast(v[r]);
        const __bf16 h = (__bf16)val;
        const __bf16 l = (__bf16)(val - (float)h);
        size_t oix;
        __bf16 *oh, *ol;
        if (id == 0) {
          oix = (size_t)row * H_ + col;
          oh = sub_h;
          ol = sub_l;
        } else if (id == 1) {
          const int lr = row - B_ * WSEG;
          const int bb = lr / TSEG;
          const int rr = lr - bb * TSEG;
          oix = ((size_t)bb * EPAD + rr) * H_ + col;
          oh = ent_h;
          ol = ent_l;
        } else {
          const int lr = row - B_ * (WSEG + TSEG);
          const int bb = lr >> 7;
          const int rr = lr & 127;
          oix = ((size_t)bb * EPAD + TSEG + rr) * H_ + col;
          oh = ent_h;
          ol = ent_l;
        }
        oh[oix] = h;
        ol[oix] = l;
      }
    }
}

// Stage 2b: ent row 152 = no_entry (hi/lo, raw); rows 153..159 zeroed.
__global__ __launch_bounds__(512) void ne_fill_kernel(
    const float* __restrict__ ne, __bf16* __restrict__ ent_h,
    __bf16* __restrict__ ent_l) {
  const int h = threadIdx.x;
  const int b = blockIdx.x;
  const float v = ne[h];
  const __bf16 hi = (__bf16)v;
  const __bf16 lo = (__bf16)(v - (float)hi);
  ent_h[((size_t)b * EPAD + 152) * H_ + h] = hi;
  ent_l[((size_t)b * EPAD + 152) * H_ + h] = lo;
#pragma unroll
  for (int r = 153; r < EPAD; ++r) {
    ent_h[((size_t)b * EPAD + r) * H_ + h] = (__bf16)0.f;
    ent_l[((size_t)b * EPAD + r) * H_ + h] = (__bf16)0.f;
  }
}

// ---------------------------------------------------------------------------
// Stage 3: att = softmax(sub @ ent^T) via split-bf16 MFMA. One block/batch.
// 4 waves in 2x2 grid: wave = 48 rows x 80 cols = 3x5 16x16 fragments.
// BK=64 staging, same GL16 + XOR-swizzle pattern as gemm3. Logits -> LDS,
// per-row wave softmax with cols >=153 masked.
// ---------------------------------------------------------------------------
__global__ __launch_bounds__(256) void attn_mfma_kernel(
    const __bf16* __restrict__ sub_h, const __bf16* __restrict__ sub_l,
    const __bf16* __restrict__ ent_h, const __bf16* __restrict__ ent_l,
    float* __restrict__ out) {
  __shared__ __align__(16) char smem[65536];
  char* sSh = smem;           // [96][64] bf16 swizzled, 12 KB
  char* sSl = smem + 12288;   // 12 KB
  char* sEh = smem + 24576;   // [160][64] bf16, 20 KB
  char* sEl = smem + 45056;   // 20 KB

  const int tid = threadIdx.x;
  const int wid = tid >> 6;
  const int lane = tid & 63;
  const int b = blockIdx.x;

  const __bf16* Sh_g = sub_h + (size_t)b * WSEG * H_;
  const __bf16* Sl_g = sub_l + (size_t)b * WSEG * H_;
  const __bf16* Eh_g = ent_h + (size_t)b * EPAD * H_;
  const __bf16* El_g = ent_l + (size_t)b * EPAD * H_;

  const int rsub = lane >> 3;
  const int csrc = (lane & 7) ^ rsub;

  const int wr = wid >> 1, wc = wid & 1;   // 2x2 wave grid
  const int arow0 = wr * 48 + (lane & 15); // M: 48 rows per wave
  const int brow0 = wc * 80 + (lane & 15); // N: 80 cols per wave
  const int cbase = (lane >> 4) * 16;
  const int sw = (lane & 7) << 4;

  f32x4 acc[3][5] = {};

#pragma unroll 1
  for (int kt = 0; kt < H_ / 64; ++kt) {
    __syncthreads();
    const size_t kofs = (size_t)kt * 64 + (size_t)csrc * 8;
    // 64 staging instrs: [0,12)=sub_h [12,24)=sub_l [24,44)=ent_h [44,64)=ent_l
#pragma unroll
    for (int j = 0; j < 16; ++j) {
      const int ig = wid * 16 + j;
      if (ig < 12) {
        GL16(Sh_g + (size_t)(ig * 8 + rsub) * H_ + kofs, sSh + ig * 1024);
      } else if (ig < 24) {
        const int i = ig - 12;
        GL16(Sl_g + (size_t)(i * 8 + rsub) * H_ + kofs, sSl + i * 1024);
      } else if (ig < 44) {
        const int i = ig - 24;
        GL16(Eh_g + (size_t)(i * 8 + rsub) * H_ + kofs, sEh + i * 1024);
      } else {
        const int i = ig - 44;
        GL16(El_g + (size_t)(i * 8 + rsub) * H_ + kofs, sEl + i * 1024);
      }
    }
    __syncthreads();

#pragma unroll
    for (int ks = 0; ks < 2; ++ks) {
      const int cc = ((cbase + ks * 64) ^ sw);
      bf16x8 ah[3], al_[3], bh[5], bl_[5];
#pragma unroll
      for (int mi = 0; mi < 3; ++mi) {
        const int off = (arow0 + mi * 16) * 128 + cc;
        ah[mi] = *(const bf16x8*)(sSh + off);
        al_[mi] = *(const bf16x8*)(sSl + off);
      }
#pragma unroll
      for (int ni = 0; ni < 5; ++ni) {
        const int off = (brow0 + ni * 16) * 128 + cc;
        bh[ni] = *(const bf16x8*)(sEh + off);
        bl_[ni] = *(const bf16x8*)(sEl + off);
      }
#pragma unroll
      for (int mi = 0; mi < 3; ++mi)
#pragma unroll
        for (int ni = 0; ni < 5; ++ni) {
          acc[mi][ni] = __builtin_amdgcn_mfma_f32_16x16x32_bf16(
              ah[mi], bh[ni], acc[mi][ni], 0, 0, 0);
          acc[mi][ni] = __builtin_amdgcn_mfma_f32_16x16x32_bf16(
              ah[mi], bl_[ni], acc[mi][ni], 0, 0, 0);
          acc[mi][ni] = __builtin_amdgcn_mfma_f32_16x16x32_bf16(
              al_[mi], bh[ni], acc[mi][ni], 0, 0, 0);
        }
    }
  }

  // logits -> LDS (reuse staging buffer)
  __syncthreads();
  float (*lg)[EPAD] = (float(*)[EPAD])smem;  // 96*160*4 = 61440 B
  const int rowb = wr * 48 + (lane >> 4) * 4;
  const int colb = wc * 80 + (lane & 15);
#pragma unroll
  for (int mi = 0; mi < 3; ++mi)
#pragma unroll
    for (int ni = 0; ni < 5; ++ni) {
      const f32x4 v = acc[mi][ni];
#pragma unroll
      for (int r = 0; r < 4; ++r)
        lg[rowb + mi * 16 + r][colb + ni * 16] = v[r];
    }
  __syncthreads();

  for (int r = wid; r < WSEG; r += 4) {
    const float x0 = lg[r][lane];
    const float x1 = lg[r][lane + 64];
    const bool has2 = (lane + 128) < ESEG;
    const float x2 = has2 ? lg[r][lane + 128] : -INFINITY;
    float m = fmaxf(fmaxf(x0, x1), x2);
#pragma unroll
    for (int off = 32; off >= 1; off >>= 1) m = fmaxf(m, __shfl_xor(m, off, 64));
    const float p0 = expf(x0 - m);
    const float p1 = expf(x1 - m);
    const float p2 = has2 ? expf(x2 - m) : 0.f;
    float ssum = p0 + p1 + p2;
#pragma unroll
    for (int off = 32; off >= 1; off >>= 1) ssum += __shfl_xor(ssum, off, 64);
    const float inv = 1.f / ssum;
    float* ob = out + ((size_t)(b * WSEG + r)) * ESEG;
    ob[lane] = p0 * inv;
    ob[lane + 64] = p1 * inv;
    if (has2) ob[lane + 128] = p2 * inv;
  }
}

// ---------------------------------------------------------------------------
extern "C" void kernel_launch(void* const* d_in, const int* in_sizes, int n_in,
                              void* d_out, int out_size, void* d_ws,
                              size_t ws_size, hipStream_t stream) {
  const float* q = (const float*)d_in[0];
  const float* Wsub = (const float*)d_in[1];
  const float* Wtab = (const float*)d_in[2];
  const float* Wcol = (const float*)d_in[3];
  const float* ne = (const float*)d_in[4];
  const int* wseg = (const int*)d_in[5];
  const int* tseg = (const int*)d_in[6];
  const int* cseg = (const int*)d_in[7];
  float* out = (float*)d_out;

  // workspace layout (bytes), peak 92.73 MB:
  char* w = (char*)d_ws;
  __bf16* Ah = (__bf16*)(w);              // 32,505,856
  __bf16* Al = (__bf16*)(w + 32505856);   // 32,505,856
  __bf16* ent_h = (__bf16*)(w + 65011712); // 10,485,760
  __bf16* ent_l = (__bf16*)(w + 75497472); // 10,485,760
  __bf16* Wth = (__bf16*)(w + 85983232);  //  3,145,728
  __bf16* Wtl = (__bf16*)(w + 89128960);  //  3,145,728
  int* lw = (int*)(w + 92274688);
  int* lt = (int*)(w + 92405760);
  int* lc = (int*)(w + 92536832);
  int* meta = (int*)(w + 92667904);       // ends 92,731,392
  // sub_h/sub_l overlay the dead tab/col region of Ah (word gemm reads only
  // Ah bytes < 12,582,912; tab/col gemm has already run by then).
  __bf16* sub_h = (__bf16*)(w + 12582912);  // 6,291,456
  __bf16* sub_l = (__bf16*)(w + 18874368);  // 6,291,456 (ends 25,165,824)

  build_csr_kernel<<<B_, 512, 0, stream>>>(wseg, tseg, cseg, lw, lt, lc, meta);
  gather_rows_kernel<<<B_ * NSEG, 256, 0, stream>>>(q, lw, lt, lc, meta, Ah,
                                                    Al);
  prep_w_kernel<<<dim3(8, 16, 3), 256, 0, stream>>>(Wsub, Wtab, Wcol, Wth,
                                                    Wtl);
  // tab+col GEMM first (reads Ah/Al rows 6144.., writes ent_h/ent_l)
  gemm3_kernel<<<dim3(4, 76), 256, 0, stream>>>(Ah, Al, Wth, Wtl, sub_h, sub_l,
                                                ent_h, ent_l, B_ * WSEG);
  ne_fill_kernel<<<B_, 512, 0, stream>>>(ne, ent_h, ent_l);
  // word GEMM (reads Ah/Al rows 0..6143, writes sub overlay)
  gemm3_kernel<<<dim3(4, 48), 256, 0, stream>>>(Ah, Al, Wth, Wtl, sub_h, sub_l,
                                                ent_h, ent_l, 0);
  attn_mfma_kernel<<<B_, 256, 0, stream>>>(sub_h, sub_l, ent_h, ent_l, out);
}